// Round 6
// baseline (491.798 us; speedup 1.0000x reference)
//
#include <hip/hip_runtime.h>
#include <hip/hip_bf16.h>
#include <math.h>

#define D_MODEL 1024
#define NHEADS  16
#define HDIM    64
#define BATCH   4
#define SEQ     2048

typedef __attribute__((ext_vector_type(8))) short bf16x8;
typedef __attribute__((ext_vector_type(4))) float f32x4;

#if __has_builtin(__builtin_amdgcn_exp2f)
#define EXP2(x) __builtin_amdgcn_exp2f(x)
#else
#define EXP2(x) exp2f(x)
#endif

__device__ __forceinline__ unsigned short f2bf(float f) {
  union { float f; unsigned u; } v; v.f = f;
  unsigned r = v.u + 0x7FFFu + ((v.u >> 16) & 1u);   // RNE
  return (unsigned short)(r >> 16);
}

__device__ __forceinline__ unsigned int pkbf(float lo, float hi) {
  __hip_bfloat162 h = __float22bfloat162_rn(float2{lo, hi});
  union { __hip_bfloat162 b; unsigned int u; } c; c.b = h;
  return c.u;
}

__device__ __forceinline__ void load_lds16(const unsigned short* g, unsigned short* l) {
  __builtin_amdgcn_global_load_lds(
      (const __attribute__((address_space(1))) unsigned int*)g,
      (__attribute__((address_space(3))) unsigned int*)l, 16, 0, 0);
}

// ---- pre-pass: fp32 -> bf16 cast (x) ----
__global__ __launch_bounds__(256) void cast_kernel(
    const float* __restrict__ in, unsigned short* __restrict__ out)
{
  const int idx = (blockIdx.x * 256 + threadIdx.x) * 8;
  float4 a = *(const float4*)&in[idx];
  float4 b = *(const float4*)&in[idx + 4];
  alignas(16) unsigned short t[8] = {
    f2bf(a.x), f2bf(a.y), f2bf(a.z), f2bf(a.w),
    f2bf(b.x), f2bf(b.y), f2bf(b.z), f2bf(b.w)};
  *(uint4*)&out[idx] = *(uint4*)t;
}

// ---- pre-pass: W [1024][N] fp32 -> WT [N][1024] bf16 ----
__global__ __launch_bounds__(256) void transpose_cast(
    const float* __restrict__ W, unsigned short* __restrict__ WT, int N)
{
  __shared__ float t[64][65];
  const int k0 = blockIdx.y * 64, n0 = blockIdx.x * 64;
  const int tid = threadIdx.x;
  const int r = tid >> 2, c0 = (tid & 3) * 16;
  #pragma unroll
  for (int i = 0; i < 16; i += 4) {
    float4 f = *(const float4*)&W[(size_t)(k0 + r) * N + n0 + c0 + i];
    t[r][c0+i] = f.x; t[r][c0+i+1] = f.y; t[r][c0+i+2] = f.z; t[r][c0+i+3] = f.w;
  }
  __syncthreads();
  #pragma unroll
  for (int i = 0; i < 16; i += 4) {
    alignas(8) unsigned short s[4] = {
      f2bf(t[c0+i][r]), f2bf(t[c0+i+1][r]), f2bf(t[c0+i+2][r]), f2bf(t[c0+i+3][r])};
    *(uint2*)&WT[(size_t)(n0 + r) * 1024 + k0 + c0 + i] = *(uint2*)s;
  }
}

// ---- m97-style GEMM: C[M x N] = A[M x 1024] @ BT[N x 1024]^T + bias ----
template<int MODE>
__global__ __launch_bounds__(256) void gemm_bt(
    const unsigned short* __restrict__ A,
    const unsigned short* __restrict__ Bt,
    const float* __restrict__ bias,
    unsigned short* __restrict__ Qb, unsigned short* __restrict__ Kb,
    unsigned short* __restrict__ Vb, float* __restrict__ Out)
{
  constexpr int N = (MODE == 0) ? 3 * D_MODEL : D_MODEL;
  const int bn = blockIdx.x * 128;
  const int bm = blockIdx.y * 128;
  const int tid  = threadIdx.x;
  const int lane = tid & 63;
  const int wave = tid >> 6;
  const int quad = lane >> 4;
  const int l16  = lane & 15;
  const int wr = wave >> 1, wc = wave & 1;

  __shared__ __align__(16) unsigned short As[128 * 64];
  __shared__ __align__(16) unsigned short Bs[128 * 64];

  f32x4 acc[4][4] = {};

  const int srow = wave * 8 + (lane >> 3);
  const int scol = (lane & 7) * 8;
  const int lbase = (wave * 8) * 64;

  for (int k0 = 0; k0 < D_MODEL; k0 += 64) {
    #pragma unroll
    for (int i = 0; i < 4; i++) {
      load_lds16(A  + (size_t)(bm + i*32 + srow) * D_MODEL + k0 + scol, &As[lbase + i*32*64]);
      load_lds16(Bt + (size_t)(bn + i*32 + srow) * D_MODEL + k0 + scol, &Bs[lbase + i*32*64]);
    }
    __syncthreads();

    #pragma unroll
    for (int kk = 0; kk < 2; kk++) {
      bf16x8 af[4], bfv[4];
      #pragma unroll
      for (int mi = 0; mi < 4; mi++)
        af[mi] = *(const bf16x8*)&As[(wr*64 + mi*16 + l16) * 64 + kk*32 + quad*8];
      #pragma unroll
      for (int ni = 0; ni < 4; ni++)
        bfv[ni] = *(const bf16x8*)&Bs[(wc*64 + ni*16 + l16) * 64 + kk*32 + quad*8];
      #pragma unroll
      for (int mi = 0; mi < 4; mi++)
        #pragma unroll
        for (int ni = 0; ni < 4; ni++)
          acc[mi][ni] = __builtin_amdgcn_mfma_f32_16x16x32_bf16(af[mi], bfv[ni], acc[mi][ni], 0, 0, 0);
    }
    __syncthreads();
  }

  const int b    = bm >> 11;
  const int tl0  = (bm & (SEQ - 1));
  #pragma unroll
  for (int ni = 0; ni < 4; ni++) {
    const int n = bn + wc*64 + ni*16 + l16;
    const float bv = bias[n];
    #pragma unroll
    for (int mi = 0; mi < 4; mi++) {
      const int t0 = tl0 + wr*64 + mi*16 + quad*4;
      if (MODE == 0) {
        const int which = n >> 10;
        const int c = n & 1023;
        const int h = c >> 6, hd = c & 63;
        const size_t bhb = ((size_t)(b*NHEADS + h)) * (SEQ*HDIM);
        if (which == 2) {
          alignas(8) unsigned short pk[4];
          #pragma unroll
          for (int r = 0; r < 4; r++) pk[r] = f2bf(acc[mi][ni][r] + bv);
          *(uint2*)&Vb[bhb + (size_t)hd*SEQ + t0] = *(uint2*)pk;
        } else if (which == 0) {
          #pragma unroll
          for (int r = 0; r < 4; r++)
            Qb[bhb + (size_t)(t0 + r)*HDIM + hd] = f2bf((acc[mi][ni][r] + bv) * 0.18033688f);
        } else {
          #pragma unroll
          for (int r = 0; r < 4; r++)
            Kb[bhb + (size_t)(t0 + r)*HDIM + hd] = f2bf(acc[mi][ni][r] + bv);
        }
      } else {
        const int m = bm + wr*64 + mi*16 + quad*4;
        #pragma unroll
        for (int r = 0; r < 4; r++)
          Out[(size_t)(m + r) * N + n] = acc[mi][ni][r] + bv;
      }
    }
  }
}

// Flash attention v6: max-free (additive partials) + split-K across wave pairs.
// Grid (bh=64, Gp=16), 4 waves/block: pair P = wave>>1 owns strip-pair
// x = Gp*2+P (32 q-rows), sub = wave&1 takes k-tiles {sub, sub+2, ...}.
// Halves: x then 63-x -> uniform ~16.5 tiles/wave. Partials merged via LDS.
__global__ __launch_bounds__(256, 4) void attn_kernel(
    const unsigned short* __restrict__ Qb,
    const unsigned short* __restrict__ Kb,
    const unsigned short* __restrict__ Vt,
    unsigned short* __restrict__ Yb)
{
  const int bh   = blockIdx.x;
  const int Gp   = blockIdx.y;
  const int tid  = threadIdx.x;
  const int wave = tid >> 6;
  const int lane = tid & 63;
  const int quad = lane >> 4;
  const int l16  = lane & 15;
  const int P    = wave >> 1;     // pair id in block
  const int sub  = wave & 1;      // k-split half

  __shared__ __align__(16) float Pl[8][16][68];   // [wave*2+strip][qrow][key/col]

  const unsigned short* __restrict__ qb_ = Qb + (size_t)bh * (SEQ*HDIM);
  const unsigned short* __restrict__ kb_ = Kb + (size_t)bh * (SEQ*HDIM);
  const unsigned short* __restrict__ vb_ = Vt + (size_t)bh * (SEQ*HDIM);
  const int h = bh & (NHEADS - 1);
  const int b = bh >> 4;
  const int x0 = Gp * 2 + P;      // 0..31

  const short ob = (short)0x3F80;
  const bf16x8 ones = {ob,ob,ob,ob,ob,ob,ob,ob};

  const int klane = l16 * HDIM + quad * 8;
  int voff[4];
  #pragma unroll
  for (int nf = 0; nf < 4; nf++) voff[nf] = (nf*16 + l16) * SEQ + quad * 8;

  // preload K tile `sub` (first tile for BOTH halves under even/odd split)
  bf16x8 kcur[2][4];
  #pragma unroll
  for (int kk = 0; kk < 2; kk++)
    #pragma unroll
    for (int nf = 0; nf < 4; nf++)
      kcur[kk][nf] = *(const bf16x8*)(kb_ + sub*(64*HDIM) + klane + nf*(16*HDIM) + kk*32);

  for (int half = 0; half < 2; half++) {
    const int x = half ? (63 - x0) : x0;
    const int qs0 = x * 32;
    const int T = (x >> 1) + 1;    // k-tiles for rows [qs0, qs0+32)

    bf16x8 qf[2][2];
    #pragma unroll
    for (int t = 0; t < 2; t++)
      #pragma unroll
      for (int kk = 0; kk < 2; kk++)
        qf[t][kk] = *(const bf16x8*)(qb_ + (qs0 + t*16 + l16)*HDIM + kk*32 + quad*8);

    f32x4 acc[2][4] = {};
    float lrow[2][4] = {};

    for (int it = sub; it < T; it += 2) {
      const int kb = it * 64;
      const bool diag = (it == T - 1);

      // V loads for this tile
      bf16x8 vcur[2][4];
      #pragma unroll
      for (int kk = 0; kk < 2; kk++)
        #pragma unroll
        for (int nf = 0; nf < 4; nf++)
          vcur[kk][nf] = *(const bf16x8*)(vb_ + voff[nf] + kb + kk*32);

      // strip 0: S
      f32x4 sfr[4] = {};
      #pragma unroll
      for (int kk = 0; kk < 2; kk++)
        #pragma unroll
        for (int nf = 0; nf < 4; nf++)
          sfr[nf] = __builtin_amdgcn_mfma_f32_16x16x32_bf16(qf[0][kk], kcur[kk][nf], sfr[nf], 0, 0, 0);
      if (diag) {
        #pragma unroll
        for (int nf = 0; nf < 4; nf++) {
          const int kcol = kb + nf*16 + l16;
          #pragma unroll
          for (int r = 0; r < 4; r++)
            sfr[nf][r] = (kcol > qs0 + quad*4 + r) ? -INFINITY : sfr[nf][r];
        }
      }
      float* P0 = &Pl[wave*2 + 0][0][0];
      #pragma unroll
      for (int nf = 0; nf < 4; nf++)
        #pragma unroll
        for (int r = 0; r < 4; r++)
          P0[(quad*4 + r)*68 + nf*16 + l16] = EXP2(sfr[nf][r]);

      // strip 1: S
      f32x4 sfr1[4] = {};
      #pragma unroll
      for (int kk = 0; kk < 2; kk++)
        #pragma unroll
        for (int nf = 0; nf < 4; nf++)
          sfr1[nf] = __builtin_amdgcn_mfma_f32_16x16x32_bf16(qf[1][kk], kcur[kk][nf], sfr1[nf], 0, 0, 0);
      if (diag) {
        #pragma unroll
        for (int nf = 0; nf < 4; nf++) {
          const int kcol = kb + nf*16 + l16;
          #pragma unroll
          for (int r = 0; r < 4; r++)
            sfr1[nf][r] = (kcol > qs0 + 16 + quad*4 + r) ? -INFINITY : sfr1[nf][r];
        }
      }
      float* P1 = &Pl[wave*2 + 1][0][0];
      #pragma unroll
      for (int nf = 0; nf < 4; nf++)
        #pragma unroll
        for (int r = 0; r < 4; r++)
          P1[(quad*4 + r)*68 + nf*16 + l16] = EXP2(sfr1[nf][r]);

      // prefetch next K tile (stride 2); on last iter, tile `sub` for next half
      {
        const int nt = (it + 2 < T) ? (it + 2) : sub;
        #pragma unroll
        for (int kk = 0; kk < 2; kk++)
          #pragma unroll
          for (int nf = 0; nf < 4; nf++)
            kcur[kk][nf] = *(const bf16x8*)(kb_ + nt*(64*HDIM) + klane + nf*(16*HDIM) + kk*32);
      }

      // PV for both strips
      #pragma unroll
      for (int t = 0; t < 2; t++) {
        const float* Pp = &Pl[wave*2 + t][0][0];
        f32x4 rsum = {};
        #pragma unroll
        for (int kk = 0; kk < 2; kk++) {
          f32x4 p0 = *(const f32x4*)&Pp[l16*68 + kk*32 + quad*8];
          f32x4 p1 = *(const f32x4*)&Pp[l16*68 + kk*32 + quad*8 + 4];
          union { unsigned int u[4]; bf16x8 v; } pk;
          pk.u[0] = pkbf(p0[0], p0[1]);
          pk.u[1] = pkbf(p0[2], p0[3]);
          pk.u[2] = pkbf(p1[0], p1[1]);
          pk.u[3] = pkbf(p1[2], p1[3]);
          const bf16x8 pf = pk.v;
          #pragma unroll
          for (int nf = 0; nf < 4; nf++)
            acc[t][nf] = __builtin_amdgcn_mfma_f32_16x16x32_bf16(pf, vcur[kk][nf], acc[t][nf], 0, 0, 0);
          rsum = __builtin_amdgcn_mfma_f32_16x16x32_bf16(pf, ones, rsum, 0, 0, 0);
        }
        #pragma unroll
        for (int r = 0; r < 4; r++) lrow[t][r] += rsum[r];
      }
    }

    // ---- merge partials across the wave pair, sub=0 finalizes ----
    if (sub == 1) {
      #pragma unroll
      for (int t = 0; t < 2; t++) {
        float* Pp = &Pl[wave*2 + t][0][0];
        #pragma unroll
        for (int r = 0; r < 4; r++) {
          const int row = quad*4 + r;
          #pragma unroll
          for (int nf = 0; nf < 4; nf++)
            Pp[row*68 + nf*16 + l16] = acc[t][nf][r];
          if (l16 == 0) Pp[row*68 + 64] = lrow[t][r];
        }
      }
    }
    __syncthreads();
    if (sub == 0) {
      #pragma unroll
      for (int t = 0; t < 2; t++) {
        const float* Pp = &Pl[(wave+1)*2 + t][0][0];   // partner strips
        #pragma unroll
        for (int r = 0; r < 4; r++) {
          const int row = quad*4 + r;
          float lr = lrow[t][r] + Pp[row*68 + 64];
          const float inv = 1.0f / lr;
          const int trow = qs0 + t*16 + row;
          const size_t off = ((size_t)(b * SEQ + trow)) * D_MODEL + h * HDIM;
          #pragma unroll
          for (int nf = 0; nf < 4; nf++)
            Yb[off + nf*16 + l16] =
                f2bf((acc[t][nf][r] + Pp[row*68 + nf*16 + l16]) * inv);
        }
      }
    }
    __syncthreads();   // protect Pl before next half's P staging
  }
}

extern "C" void kernel_launch(void* const* d_in, const int* in_sizes, int n_in,
                              void* d_out, int out_size, void* d_ws, size_t ws_size,
                              hipStream_t stream) {
  const float* x     = (const float*)d_in[0];
  const float* w_qkv = (const float*)d_in[1];
  const float* b_qkv = (const float*)d_in[2];
  const float* w_out = (const float*)d_in[3];
  const float* b_out = (const float*)d_in[4];
  float* out = (float*)d_out;

  const size_t SZ = (size_t)BATCH * NHEADS * SEQ * HDIM;   // 8M elems
  unsigned short* Qb  = (unsigned short*)d_ws;             // 16 MiB
  unsigned short* Kb  = Qb + SZ;                           // 16 MiB
  unsigned short* Vb  = Kb + SZ;                           // 16 MiB (V^T)
  unsigned short* Xb  = Vb + SZ;                           // 16 MiB, aliased by Yb
  unsigned short* Yb  = Xb;                                // attn writes after gemm0 reads
  unsigned short* WqT = Xb + SZ;                           // 6 MiB
  unsigned short* WoT = WqT + (size_t)3*D_MODEL*D_MODEL;   // 2 MiB

  cast_kernel<<<dim3((BATCH*SEQ*D_MODEL)/(256*8)), 256, 0, stream>>>(x, Xb);
  transpose_cast<<<dim3(3*D_MODEL/64, D_MODEL/64), 256, 0, stream>>>(w_qkv, WqT, 3*D_MODEL);
  transpose_cast<<<dim3(D_MODEL/64, D_MODEL/64), 256, 0, stream>>>(w_out, WoT, D_MODEL);

  gemm_bt<0><<<dim3(3*D_MODEL/128, BATCH*SEQ/128), 256, 0, stream>>>(
      Xb, WqT, b_qkv, Qb, Kb, Vb, nullptr);
  attn_kernel<<<dim3(BATCH*NHEADS, 16), 256, 0, stream>>>(Qb, Kb, Vb, Yb);
  gemm_bt<1><<<dim3(D_MODEL/128, BATCH*SEQ/128), 256, 0, stream>>>(
      Yb, WoT, b_out, nullptr, nullptr, nullptr, out);
}

// Round 7
// 331.584 us; speedup vs baseline: 1.4832x; 1.4832x over previous
//
#include <hip/hip_runtime.h>
#include <hip/hip_bf16.h>
#include <math.h>

#define D_MODEL 1024
#define NHEADS  16
#define HDIM    64
#define BATCH   4
#define SEQ     2048

typedef __attribute__((ext_vector_type(8))) short bf16x8;
typedef __attribute__((ext_vector_type(4))) float f32x4;

#if __has_builtin(__builtin_amdgcn_exp2f)
#define EXP2(x) __builtin_amdgcn_exp2f(x)
#else
#define EXP2(x) exp2f(x)
#endif

#if __has_builtin(__builtin_amdgcn_sched_barrier)
#define SCHED_FENCE() __builtin_amdgcn_sched_barrier(0)
#else
#define SCHED_FENCE()
#endif

__device__ __forceinline__ unsigned short f2bf(float f) {
  union { float f; unsigned u; } v; v.f = f;
  unsigned r = v.u + 0x7FFFu + ((v.u >> 16) & 1u);   // RNE
  return (unsigned short)(r >> 16);
}

__device__ __forceinline__ unsigned int pkbf(float lo, float hi) {
  __hip_bfloat162 h = __float22bfloat162_rn(float2{lo, hi});
  union { __hip_bfloat162 b; unsigned int u; } c; c.b = h;
  return c.u;
}

__device__ __forceinline__ void load_lds16(const unsigned short* g, unsigned short* l) {
  __builtin_amdgcn_global_load_lds(
      (const __attribute__((address_space(1))) unsigned int*)g,
      (__attribute__((address_space(3))) unsigned int*)l, 16, 0, 0);
}

// ---- pre-pass: fp32 -> bf16 cast (x) ----
__global__ __launch_bounds__(256) void cast_kernel(
    const float* __restrict__ in, unsigned short* __restrict__ out)
{
  const int idx = (blockIdx.x * 256 + threadIdx.x) * 8;
  float4 a = *(const float4*)&in[idx];
  float4 b = *(const float4*)&in[idx + 4];
  alignas(16) unsigned short t[8] = {
    f2bf(a.x), f2bf(a.y), f2bf(a.z), f2bf(a.w),
    f2bf(b.x), f2bf(b.y), f2bf(b.z), f2bf(b.w)};
  *(uint4*)&out[idx] = *(uint4*)t;
}

// ---- pre-pass: W [1024][N] fp32 -> WT [N][1024] bf16 ----
__global__ __launch_bounds__(256) void transpose_cast(
    const float* __restrict__ W, unsigned short* __restrict__ WT, int N)
{
  __shared__ float t[64][65];
  const int k0 = blockIdx.y * 64, n0 = blockIdx.x * 64;
  const int tid = threadIdx.x;
  const int r = tid >> 2, c0 = (tid & 3) * 16;
  #pragma unroll
  for (int i = 0; i < 16; i += 4) {
    float4 f = *(const float4*)&W[(size_t)(k0 + r) * N + n0 + c0 + i];
    t[r][c0+i] = f.x; t[r][c0+i+1] = f.y; t[r][c0+i+2] = f.z; t[r][c0+i+3] = f.w;
  }
  __syncthreads();
  #pragma unroll
  for (int i = 0; i < 16; i += 4) {
    alignas(8) unsigned short s[4] = {
      f2bf(t[c0+i][r]), f2bf(t[c0+i+1][r]), f2bf(t[c0+i+2][r]), f2bf(t[c0+i+3][r])};
    *(uint2*)&WT[(size_t)(n0 + r) * 1024 + k0 + c0 + i] = *(uint2*)s;
  }
}

// ---- m97-style GEMM: C[M x N] = A[M x 1024] @ BT[N x 1024]^T + bias ----
template<int MODE>
__global__ __launch_bounds__(256) void gemm_bt(
    const unsigned short* __restrict__ A,
    const unsigned short* __restrict__ Bt,
    const float* __restrict__ bias,
    unsigned short* __restrict__ Qb, unsigned short* __restrict__ Kb,
    unsigned short* __restrict__ Vb, float* __restrict__ Out)
{
  constexpr int N = (MODE == 0) ? 3 * D_MODEL : D_MODEL;
  const int bn = blockIdx.x * 128;
  const int bm = blockIdx.y * 128;
  const int tid  = threadIdx.x;
  const int lane = tid & 63;
  const int wave = tid >> 6;
  const int quad = lane >> 4;
  const int l16  = lane & 15;
  const int wr = wave >> 1, wc = wave & 1;

  __shared__ __align__(16) unsigned short As[128 * 64];
  __shared__ __align__(16) unsigned short Bs[128 * 64];

  f32x4 acc[4][4] = {};

  const int srow = wave * 8 + (lane >> 3);
  const int scol = (lane & 7) * 8;
  const int lbase = (wave * 8) * 64;

  for (int k0 = 0; k0 < D_MODEL; k0 += 64) {
    #pragma unroll
    for (int i = 0; i < 4; i++) {
      load_lds16(A  + (size_t)(bm + i*32 + srow) * D_MODEL + k0 + scol, &As[lbase + i*32*64]);
      load_lds16(Bt + (size_t)(bn + i*32 + srow) * D_MODEL + k0 + scol, &Bs[lbase + i*32*64]);
    }
    __syncthreads();

    #pragma unroll
    for (int kk = 0; kk < 2; kk++) {
      bf16x8 af[4], bfv[4];
      #pragma unroll
      for (int mi = 0; mi < 4; mi++)
        af[mi] = *(const bf16x8*)&As[(wr*64 + mi*16 + l16) * 64 + kk*32 + quad*8];
      #pragma unroll
      for (int ni = 0; ni < 4; ni++)
        bfv[ni] = *(const bf16x8*)&Bs[(wc*64 + ni*16 + l16) * 64 + kk*32 + quad*8];
      #pragma unroll
      for (int mi = 0; mi < 4; mi++)
        #pragma unroll
        for (int ni = 0; ni < 4; ni++)
          acc[mi][ni] = __builtin_amdgcn_mfma_f32_16x16x32_bf16(af[mi], bfv[ni], acc[mi][ni], 0, 0, 0);
    }
    __syncthreads();
  }

  const int b    = bm >> 11;
  const int tl0  = (bm & (SEQ - 1));
  #pragma unroll
  for (int ni = 0; ni < 4; ni++) {
    const int n = bn + wc*64 + ni*16 + l16;
    const float bv = bias[n];
    #pragma unroll
    for (int mi = 0; mi < 4; mi++) {
      const int t0 = tl0 + wr*64 + mi*16 + quad*4;
      if (MODE == 0) {
        const int which = n >> 10;
        const int c = n & 1023;
        const int h = c >> 6, hd = c & 63;
        const size_t bhb = ((size_t)(b*NHEADS + h)) * (SEQ*HDIM);
        if (which == 2) {
          alignas(8) unsigned short pk[4];
          #pragma unroll
          for (int r = 0; r < 4; r++) pk[r] = f2bf(acc[mi][ni][r] + bv);
          *(uint2*)&Vb[bhb + (size_t)hd*SEQ + t0] = *(uint2*)pk;
        } else if (which == 0) {
          #pragma unroll
          for (int r = 0; r < 4; r++)
            Qb[bhb + (size_t)(t0 + r)*HDIM + hd] = f2bf((acc[mi][ni][r] + bv) * 0.18033688f);
        } else {
          #pragma unroll
          for (int r = 0; r < 4; r++)
            Kb[bhb + (size_t)(t0 + r)*HDIM + hd] = f2bf(acc[mi][ni][r] + bv);
        }
      } else {
        const int m = bm + wr*64 + mi*16 + quad*4;
        #pragma unroll
        for (int r = 0; r < 4; r++)
          Out[(size_t)(m + r) * N + n] = acc[mi][ni][r] + bv;
      }
    }
  }
}

// Flash attention v7: R5 structure + sched_barrier load batching.
// Barrier-free, max-free, 32 q-rows/wave. Grid (bh=64, Gp=8); wave w:
// strip-pair x = 4Gp+w then 63-x -> uniform 33 k-tiles.
// Per iter: [V loads] FENCE [S0,S1 MFMAs] [K prefetch] FENCE [exp2/LDS/PV].
__global__ __launch_bounds__(256, 2) void attn_kernel(
    const unsigned short* __restrict__ Qb,
    const unsigned short* __restrict__ Kb,
    const unsigned short* __restrict__ Vt,
    unsigned short* __restrict__ Yb)
{
  const int bh   = blockIdx.x;
  const int Gp   = blockIdx.y;
  const int tid  = threadIdx.x;
  const int wave = tid >> 6;
  const int lane = tid & 63;
  const int quad = lane >> 4;
  const int l16  = lane & 15;

  __shared__ __align__(16) float Pl[8][16][68];   // [wave*2+strip][qrow][key]

  const unsigned short* __restrict__ qb_ = Qb + (size_t)bh * (SEQ*HDIM);
  const unsigned short* __restrict__ kb_ = Kb + (size_t)bh * (SEQ*HDIM);
  const unsigned short* __restrict__ vb_ = Vt + (size_t)bh * (SEQ*HDIM);
  const int h = bh & (NHEADS - 1);
  const int b = bh >> 4;

  const short ob = (short)0x3F80;    // bf16 1.0
  const bf16x8 ones = {ob,ob,ob,ob,ob,ob,ob,ob};

  const int klane = l16 * HDIM + quad * 8;
  int voff[4];
  #pragma unroll
  for (int nf = 0; nf < 4; nf++) voff[nf] = (nf*16 + l16) * SEQ + quad * 8;

  // preload K tile 0 (consumed by each half's first iteration)
  bf16x8 kcur[2][4];
  #pragma unroll
  for (int kk = 0; kk < 2; kk++)
    #pragma unroll
    for (int nf = 0; nf < 4; nf++)
      kcur[kk][nf] = *(const bf16x8*)(kb_ + klane + nf*(16*HDIM) + kk*32);

  for (int half = 0; half < 2; half++) {
    const int x = half ? (63 - (Gp*4 + wave)) : (Gp*4 + wave);  // strip-pair id
    const int qs0 = x * 32;
    const int ntiles = (x >> 1) + 1;

    bf16x8 qf[2][2];
    #pragma unroll
    for (int t = 0; t < 2; t++)
      #pragma unroll
      for (int kk = 0; kk < 2; kk++)
        qf[t][kk] = *(const bf16x8*)(qb_ + (qs0 + t*16 + l16)*HDIM + kk*32 + quad*8);

    f32x4 acc[2][4] = {};
    float lrow[2][4] = {};

    for (int it = 0; it < ntiles; it++) {
      const int kb = it * 64;
      const bool last = (it == ntiles - 1);

      // ---- batch-issue V loads for this tile ----
      bf16x8 vcur[2][4];
      #pragma unroll
      for (int kk = 0; kk < 2; kk++)
        #pragma unroll
        for (int nf = 0; nf < 4; nf++)
          vcur[kk][nf] = *(const bf16x8*)(vb_ + voff[nf] + kb + kk*32);
      SCHED_FENCE();   // pin V loads at iteration top (no sinking)

      // ---- S for both strips from prefetched kcur ----
      f32x4 sfr[4] = {}, sfr1[4] = {};
      #pragma unroll
      for (int kk = 0; kk < 2; kk++)
        #pragma unroll
        for (int nf = 0; nf < 4; nf++)
          sfr[nf] = __builtin_amdgcn_mfma_f32_16x16x32_bf16(qf[0][kk], kcur[kk][nf], sfr[nf], 0, 0, 0);
      #pragma unroll
      for (int kk = 0; kk < 2; kk++)
        #pragma unroll
        for (int nf = 0; nf < 4; nf++)
          sfr1[nf] = __builtin_amdgcn_mfma_f32_16x16x32_bf16(qf[1][kk], kcur[kk][nf], sfr1[nf], 0, 0, 0);

      // ---- batch-issue next K tile (tile 0 of next half on last iter) ----
      {
        const int nko = last ? 0 : (it + 1) * (64*HDIM);
        #pragma unroll
        for (int kk = 0; kk < 2; kk++)
          #pragma unroll
          for (int nf = 0; nf < 4; nf++)
            kcur[kk][nf] = *(const bf16x8*)(kb_ + nko + klane + nf*(16*HDIM) + kk*32);
      }
      SCHED_FENCE();   // pin K prefetch before the consume phase

      // ---- causal mask (diagonal tile only) ----
      if (last) {
        #pragma unroll
        for (int nf = 0; nf < 4; nf++) {
          const int kcol = kb + nf*16 + l16;
          #pragma unroll
          for (int r = 0; r < 4; r++) {
            sfr[nf][r]  = (kcol > qs0 + quad*4 + r)      ? -INFINITY : sfr[nf][r];
            sfr1[nf][r] = (kcol > qs0 + 16 + quad*4 + r) ? -INFINITY : sfr1[nf][r];
          }
        }
      }

      // ---- P = exp2(S) -> per-wave LDS (C-layout -> A-layout) ----
      float* P0 = &Pl[wave*2 + 0][0][0];
      float* P1 = &Pl[wave*2 + 1][0][0];
      #pragma unroll
      for (int nf = 0; nf < 4; nf++)
        #pragma unroll
        for (int r = 0; r < 4; r++) {
          P0[(quad*4 + r)*68 + nf*16 + l16] = EXP2(sfr[nf][r]);
          P1[(quad*4 + r)*68 + nf*16 + l16] = EXP2(sfr1[nf][r]);
        }

      // ---- PV for both strips ----
      #pragma unroll
      for (int t = 0; t < 2; t++) {
        const float* Pp = &Pl[wave*2 + t][0][0];
        f32x4 rsum = {};
        #pragma unroll
        for (int kk = 0; kk < 2; kk++) {
          f32x4 p0 = *(const f32x4*)&Pp[l16*68 + kk*32 + quad*8];
          f32x4 p1 = *(const f32x4*)&Pp[l16*68 + kk*32 + quad*8 + 4];
          union { unsigned int u[4]; bf16x8 v; } pk;
          pk.u[0] = pkbf(p0[0], p0[1]);
          pk.u[1] = pkbf(p0[2], p0[3]);
          pk.u[2] = pkbf(p1[0], p1[1]);
          pk.u[3] = pkbf(p1[2], p1[3]);
          const bf16x8 pf = pk.v;
          #pragma unroll
          for (int nf = 0; nf < 4; nf++)
            acc[t][nf] = __builtin_amdgcn_mfma_f32_16x16x32_bf16(pf, vcur[kk][nf], acc[t][nf], 0, 0, 0);
          rsum = __builtin_amdgcn_mfma_f32_16x16x32_bf16(pf, ones, rsum, 0, 0, 0);
        }
        #pragma unroll
        for (int r = 0; r < 4; r++) lrow[t][r] += rsum[r];
      }
    }

    // ---- O /= l, write y (B,T,C) bf16 ----
    #pragma unroll
    for (int t = 0; t < 2; t++) {
      #pragma unroll
      for (int r = 0; r < 4; r++) {
        const float inv = 1.0f / lrow[t][r];
        const int trow = qs0 + t*16 + quad*4 + r;
        const size_t off = ((size_t)(b * SEQ + trow)) * D_MODEL + h * HDIM;
        #pragma unroll
        for (int nf = 0; nf < 4; nf++)
          Yb[off + nf*16 + l16] = f2bf(acc[t][nf][r] * inv);
      }
    }
  }
}

extern "C" void kernel_launch(void* const* d_in, const int* in_sizes, int n_in,
                              void* d_out, int out_size, void* d_ws, size_t ws_size,
                              hipStream_t stream) {
  const float* x     = (const float*)d_in[0];
  const float* w_qkv = (const float*)d_in[1];
  const float* b_qkv = (const float*)d_in[2];
  const float* w_out = (const float*)d_in[3];
  const float* b_out = (const float*)d_in[4];
  float* out = (float*)d_out;

  const size_t SZ = (size_t)BATCH * NHEADS * SEQ * HDIM;   // 8M elems
  unsigned short* Qb  = (unsigned short*)d_ws;             // 16 MiB
  unsigned short* Kb  = Qb + SZ;                           // 16 MiB
  unsigned short* Vb  = Kb + SZ;                           // 16 MiB (V^T)
  unsigned short* Xb  = Vb + SZ;                           // 16 MiB, aliased by Yb
  unsigned short* Yb  = Xb;                                // attn writes after gemm0 reads
  unsigned short* WqT = Xb + SZ;                           // 6 MiB
  unsigned short* WoT = WqT + (size_t)3*D_MODEL*D_MODEL;   // 2 MiB

  cast_kernel<<<dim3((BATCH*SEQ*D_MODEL)/(256*8)), 256, 0, stream>>>(x, Xb);
  transpose_cast<<<dim3(3*D_MODEL/64, D_MODEL/64), 256, 0, stream>>>(w_qkv, WqT, 3*D_MODEL);
  transpose_cast<<<dim3(D_MODEL/64, D_MODEL/64), 256, 0, stream>>>(w_out, WoT, D_MODEL);

  gemm_bt<0><<<dim3(3*D_MODEL/128, BATCH*SEQ/128), 256, 0, stream>>>(
      Xb, WqT, b_qkv, Qb, Kb, Vb, nullptr);
  attn_kernel<<<dim3(BATCH*NHEADS, 8), 256, 0, stream>>>(Qb, Kb, Vb, Yb);
  gemm_bt<1><<<dim3(D_MODEL/128, BATCH*SEQ/128), 256, 0, stream>>>(
      Yb, WoT, b_out, nullptr, nullptr, nullptr, out);
}

// Round 8
// 287.366 us; speedup vs baseline: 1.7114x; 1.1539x over previous
//
#include <hip/hip_runtime.h>
#include <hip/hip_bf16.h>
#include <math.h>

#define D_MODEL 1024
#define NHEADS  16
#define HDIM    64
#define BATCH   4
#define SEQ     2048

typedef __attribute__((ext_vector_type(8))) short bf16x8;
typedef __attribute__((ext_vector_type(4))) float f32x4;

#if __has_builtin(__builtin_amdgcn_exp2f)
#define EXP2(x) __builtin_amdgcn_exp2f(x)
#else
#define EXP2(x) exp2f(x)
#endif

__device__ __forceinline__ unsigned short f2bf(float f) {
  union { float f; unsigned u; } v; v.f = f;
  unsigned r = v.u + 0x7FFFu + ((v.u >> 16) & 1u);   // RNE
  return (unsigned short)(r >> 16);
}

__device__ __forceinline__ void load_lds16(const unsigned short* g, unsigned short* l) {
  __builtin_amdgcn_global_load_lds(
      (const __attribute__((address_space(1))) unsigned int*)g,
      (__attribute__((address_space(3))) unsigned int*)l, 16, 0, 0);
}

// ---- pre-pass: fp32 -> bf16 cast (x) ----
__global__ __launch_bounds__(256) void cast_kernel(
    const float* __restrict__ in, unsigned short* __restrict__ out)
{
  const int idx = (blockIdx.x * 256 + threadIdx.x) * 8;
  float4 a = *(const float4*)&in[idx];
  float4 b = *(const float4*)&in[idx + 4];
  alignas(16) unsigned short t[8] = {
    f2bf(a.x), f2bf(a.y), f2bf(a.z), f2bf(a.w),
    f2bf(b.x), f2bf(b.y), f2bf(b.z), f2bf(b.w)};
  *(uint4*)&out[idx] = *(uint4*)t;
}

// ---- pre-pass: W [1024][N] fp32 -> WT [N][1024] bf16 ----
__global__ __launch_bounds__(256) void transpose_cast(
    const float* __restrict__ W, unsigned short* __restrict__ WT, int N)
{
  __shared__ float t[64][65];
  const int k0 = blockIdx.y * 64, n0 = blockIdx.x * 64;
  const int tid = threadIdx.x;
  const int r = tid >> 2, c0 = (tid & 3) * 16;
  #pragma unroll
  for (int i = 0; i < 16; i += 4) {
    float4 f = *(const float4*)&W[(size_t)(k0 + r) * N + n0 + c0 + i];
    t[r][c0+i] = f.x; t[r][c0+i+1] = f.y; t[r][c0+i+2] = f.z; t[r][c0+i+3] = f.w;
  }
  __syncthreads();
  #pragma unroll
  for (int i = 0; i < 16; i += 4) {
    alignas(8) unsigned short s[4] = {
      f2bf(t[c0+i][r]), f2bf(t[c0+i+1][r]), f2bf(t[c0+i+2][r]), f2bf(t[c0+i+3][r])};
    *(uint2*)&WT[(size_t)(n0 + r) * 1024 + k0 + c0 + i] = *(uint2*)s;
  }
}

// ---- m97-style GEMM: C[M x N] = A[M x 1024] @ BT[N x 1024]^T + bias ----
template<int MODE>
__global__ __launch_bounds__(256) void gemm_bt(
    const unsigned short* __restrict__ A,
    const unsigned short* __restrict__ Bt,
    const float* __restrict__ bias,
    unsigned short* __restrict__ Qb, unsigned short* __restrict__ Kb,
    unsigned short* __restrict__ Vb, float* __restrict__ Out)
{
  constexpr int N = (MODE == 0) ? 3 * D_MODEL : D_MODEL;
  const int bn = blockIdx.x * 128;
  const int bm = blockIdx.y * 128;
  const int tid  = threadIdx.x;
  const int lane = tid & 63;
  const int wave = tid >> 6;
  const int quad = lane >> 4;
  const int l16  = lane & 15;
  const int wr = wave >> 1, wc = wave & 1;

  __shared__ __align__(16) unsigned short As[128 * 64];
  __shared__ __align__(16) unsigned short Bs[128 * 64];

  f32x4 acc[4][4] = {};

  const int srow = wave * 8 + (lane >> 3);
  const int scol = (lane & 7) * 8;
  const int lbase = (wave * 8) * 64;

  for (int k0 = 0; k0 < D_MODEL; k0 += 64) {
    #pragma unroll
    for (int i = 0; i < 4; i++) {
      load_lds16(A  + (size_t)(bm + i*32 + srow) * D_MODEL + k0 + scol, &As[lbase + i*32*64]);
      load_lds16(Bt + (size_t)(bn + i*32 + srow) * D_MODEL + k0 + scol, &Bs[lbase + i*32*64]);
    }
    __syncthreads();

    #pragma unroll
    for (int kk = 0; kk < 2; kk++) {
      bf16x8 af[4], bfv[4];
      #pragma unroll
      for (int mi = 0; mi < 4; mi++)
        af[mi] = *(const bf16x8*)&As[(wr*64 + mi*16 + l16) * 64 + kk*32 + quad*8];
      #pragma unroll
      for (int ni = 0; ni < 4; ni++)
        bfv[ni] = *(const bf16x8*)&Bs[(wc*64 + ni*16 + l16) * 64 + kk*32 + quad*8];
      #pragma unroll
      for (int mi = 0; mi < 4; mi++)
        #pragma unroll
        for (int ni = 0; ni < 4; ni++)
          acc[mi][ni] = __builtin_amdgcn_mfma_f32_16x16x32_bf16(af[mi], bfv[ni], acc[mi][ni], 0, 0, 0);
    }
    __syncthreads();
  }

  const int b    = bm >> 11;
  const int tl0  = (bm & (SEQ - 1));
  #pragma unroll
  for (int ni = 0; ni < 4; ni++) {
    const int n = bn + wc*64 + ni*16 + l16;
    const float bv = bias[n];
    #pragma unroll
    for (int mi = 0; mi < 4; mi++) {
      const int t0 = tl0 + wr*64 + mi*16 + quad*4;
      if (MODE == 0) {
        const int which = n >> 10;
        const int c = n & 1023;
        const int h = c >> 6, hd = c & 63;
        const size_t bhb = ((size_t)(b*NHEADS + h)) * (SEQ*HDIM);
        if (which == 2) {
          alignas(8) unsigned short pk[4];
          #pragma unroll
          for (int r = 0; r < 4; r++) pk[r] = f2bf(acc[mi][ni][r] + bv);
          *(uint2*)&Vb[bhb + (size_t)hd*SEQ + t0] = *(uint2*)pk;
        } else if (which == 0) {
          #pragma unroll
          for (int r = 0; r < 4; r++)
            Qb[bhb + (size_t)(t0 + r)*HDIM + hd] = f2bf((acc[mi][ni][r] + bv) * 0.18033688f);
        } else {
          #pragma unroll
          for (int r = 0; r < 4; r++)
            Kb[bhb + (size_t)(t0 + r)*HDIM + hd] = f2bf(acc[mi][ni][r] + bv);
        }
      } else {
        const int m = bm + wr*64 + mi*16 + quad*4;
        #pragma unroll
        for (int r = 0; r < 4; r++)
          Out[(size_t)(m + r) * N + n] = acc[mi][ni][r] + bv;
      }
    }
  }
}

// Flash attention v8: block-cooperative, m97-style LDS staging.
// Grid (bh=64, Gp=8). Block = 4 waves = 128 q-rows; wave w owns rows
// [qt*128 + 32w, +32) (two 16-row strips). Halves qt = Gp then 15-Gp ->
// uniform 34 k-tiles/block. Per tile: stage K[key][hd] + V^T[hd][key] into
// LDS via global_load_lds(16B), barrier, S/softmax(max-free)/PV, barrier.
__global__ __launch_bounds__(256) void attn_kernel(
    const unsigned short* __restrict__ Qb,
    const unsigned short* __restrict__ Kb,
    const unsigned short* __restrict__ Vt,
    unsigned short* __restrict__ Yb)
{
  const int bh   = blockIdx.x;
  const int Gp   = blockIdx.y;
  const int tid  = threadIdx.x;
  const int wave = tid >> 6;
  const int lane = tid & 63;
  const int quad = lane >> 4;
  const int l16  = lane & 15;

  __shared__ __align__(16) unsigned short Ks[64 * 64];      // [key][hd]
  __shared__ __align__(16) unsigned short Vs[64 * 64];      // [hd][key]
  __shared__ __align__(16) unsigned short Pl[8][16][72];    // per-strip P (bf16)

  const unsigned short* __restrict__ qb_ = Qb + (size_t)bh * (SEQ*HDIM);
  const unsigned short* __restrict__ kb_ = Kb + (size_t)bh * (SEQ*HDIM);
  const unsigned short* __restrict__ vb_ = Vt + (size_t)bh * (SEQ*HDIM);
  const int h = bh & (NHEADS - 1);
  const int b = bh >> 4;

  const short ob = (short)0x3F80;    // bf16 1.0
  const bf16x8 ones = {ob,ob,ob,ob,ob,ob,ob,ob};

  // staging addresses (lane-invariant parts)
  const int kst = wave * 1024 + lane * 8;            // K: flat 8KB copy
  const int vrow = wave * 16 + (lane >> 3);          // V: hd row base
  const int vcol = (lane & 7) * 8;

  for (int half = 0; half < 2; half++) {
    const int qt = half ? (15 - Gp) : Gp;
    const int ntiles = 2 * qt + 2;
    const int qs0 = qt * 128 + wave * 32;
    const int myLast = 2 * qt + (wave >> 1);         // last tile this wave needs

    bf16x8 qf[2][2];
    #pragma unroll
    for (int t = 0; t < 2; t++)
      #pragma unroll
      for (int kk = 0; kk < 2; kk++)
        qf[t][kk] = *(const bf16x8*)(qb_ + (qs0 + t*16 + l16)*HDIM + kk*32 + quad*8);

    f32x4 acc[2][4] = {};
    float lrow[2][4] = {};

    for (int it = 0; it < ntiles; it++) {
      const int kb = it * 64;

      // ---- stage K tile (flat 8KB) and V^T tile (64 rows x 128B) ----
      #pragma unroll
      for (int j = 0; j < 2; j++)
        load_lds16(kb_ + (size_t)kb*HDIM + kst + j*512, &Ks[wave*1024 + j*512]);
      #pragma unroll
      for (int j = 0; j < 2; j++)
        load_lds16(vb_ + (size_t)(vrow + j*8)*SEQ + kb + vcol, &Vs[(wave*16 + j*8)*64]);
      __syncthreads();

      if (it <= myLast) {
        // ---- S for both strips (K-frag shared) ----
        f32x4 sfr[4] = {}, sfr1[4] = {};
        #pragma unroll
        for (int kk = 0; kk < 2; kk++)
          #pragma unroll
          for (int nf = 0; nf < 4; nf++) {
            const bf16x8 kf = *(const bf16x8*)&Ks[(nf*16 + l16)*64 + kk*32 + quad*8];
            sfr[nf]  = __builtin_amdgcn_mfma_f32_16x16x32_bf16(qf[0][kk], kf, sfr[nf], 0, 0, 0);
            sfr1[nf] = __builtin_amdgcn_mfma_f32_16x16x32_bf16(qf[1][kk], kf, sfr1[nf], 0, 0, 0);
          }

        // ---- causal mask on this wave's diagonal tile only ----
        if (it == myLast) {
          #pragma unroll
          for (int nf = 0; nf < 4; nf++) {
            const int kcol = kb + nf*16 + l16;
            #pragma unroll
            for (int r = 0; r < 4; r++) {
              sfr[nf][r]  = (kcol > qs0 + quad*4 + r)      ? -INFINITY : sfr[nf][r];
              sfr1[nf][r] = (kcol > qs0 + 16 + quad*4 + r) ? -INFINITY : sfr1[nf][r];
            }
          }
        }

        // ---- P = exp2(S) -> per-wave LDS bf16 (C-layout -> A-layout) ----
        #pragma unroll
        for (int nf = 0; nf < 4; nf++)
          #pragma unroll
          for (int r = 0; r < 4; r++) {
            Pl[wave*2 + 0][quad*4 + r][nf*16 + l16] = f2bf(EXP2(sfr[nf][r]));
            Pl[wave*2 + 1][quad*4 + r][nf*16 + l16] = f2bf(EXP2(sfr1[nf][r]));
          }

        // ---- PV for both strips (V-frags from LDS) ----
        #pragma unroll
        for (int t = 0; t < 2; t++) {
          f32x4 rsum = {};
          #pragma unroll
          for (int kk = 0; kk < 2; kk++) {
            const bf16x8 pf = *(const bf16x8*)&Pl[wave*2 + t][l16][kk*32 + quad*8];
            #pragma unroll
            for (int nf = 0; nf < 4; nf++) {
              const bf16x8 vf = *(const bf16x8*)&Vs[(nf*16 + l16)*64 + kk*32 + quad*8];
              acc[t][nf] = __builtin_amdgcn_mfma_f32_16x16x32_bf16(pf, vf, acc[t][nf], 0, 0, 0);
            }
            rsum = __builtin_amdgcn_mfma_f32_16x16x32_bf16(pf, ones, rsum, 0, 0, 0);
          }
          #pragma unroll
          for (int r = 0; r < 4; r++) lrow[t][r] += rsum[r];
        }
      }
      __syncthreads();   // protect Ks/Vs before next staging
    }

    // ---- O /= l, write y (B,T,C) bf16 ----
    #pragma unroll
    for (int t = 0; t < 2; t++) {
      #pragma unroll
      for (int r = 0; r < 4; r++) {
        const float inv = 1.0f / lrow[t][r];
        const int trow = qs0 + t*16 + quad*4 + r;
        const size_t off = ((size_t)(b * SEQ + trow)) * D_MODEL + h * HDIM;
        #pragma unroll
        for (int nf = 0; nf < 4; nf++)
          Yb[off + nf*16 + l16] = f2bf(acc[t][nf][r] * inv);
      }
    }
  }
}

extern "C" void kernel_launch(void* const* d_in, const int* in_sizes, int n_in,
                              void* d_out, int out_size, void* d_ws, size_t ws_size,
                              hipStream_t stream) {
  const float* x     = (const float*)d_in[0];
  const float* w_qkv = (const float*)d_in[1];
  const float* b_qkv = (const float*)d_in[2];
  const float* w_out = (const float*)d_in[3];
  const float* b_out = (const float*)d_in[4];
  float* out = (float*)d_out;

  const size_t SZ = (size_t)BATCH * NHEADS * SEQ * HDIM;   // 8M elems
  unsigned short* Qb  = (unsigned short*)d_ws;             // 16 MiB
  unsigned short* Kb  = Qb + SZ;                           // 16 MiB
  unsigned short* Vb  = Kb + SZ;                           // 16 MiB (V^T)
  unsigned short* Xb  = Vb + SZ;                           // 16 MiB, aliased by Yb
  unsigned short* Yb  = Xb;                                // attn writes after gemm0 reads
  unsigned short* WqT = Xb + SZ;                           // 6 MiB
  unsigned short* WoT = WqT + (size_t)3*D_MODEL*D_MODEL;   // 2 MiB

  cast_kernel<<<dim3((BATCH*SEQ*D_MODEL)/(256*8)), 256, 0, stream>>>(x, Xb);
  transpose_cast<<<dim3(3*D_MODEL/64, D_MODEL/64), 256, 0, stream>>>(w_qkv, WqT, 3*D_MODEL);
  transpose_cast<<<dim3(D_MODEL/64, D_MODEL/64), 256, 0, stream>>>(w_out, WoT, D_MODEL);

  gemm_bt<0><<<dim3(3*D_MODEL/128, BATCH*SEQ/128), 256, 0, stream>>>(
      Xb, WqT, b_qkv, Qb, Kb, Vb, nullptr);
  attn_kernel<<<dim3(BATCH*NHEADS, 8), 256, 0, stream>>>(Qb, Kb, Vb, Yb);
  gemm_bt<1><<<dim3(D_MODEL/128, BATCH*SEQ/128), 256, 0, stream>>>(
      Yb, WoT, b_out, nullptr, nullptr, nullptr, out);
}